// Round 1
// baseline (40.533 us; speedup 1.0000x reference)
//
#include <hip/hip_runtime.h>

// Geometry: 512*512 letters, each 16x8 = 128 fp32; 3x3 VALID conv -> 14x6 = 84 outputs.
#define BLOCK 256
#define LETTERS_PER_BLOCK 64
#define LETTER_SZ 128                 // floats per letter
#define OUT_PER_LETTER 84
#define OUT_PER_BLOCK (LETTERS_PER_BLOCK * OUT_PER_LETTER)   // 5376
#define IN_FLOATS_PER_BLOCK (LETTERS_PER_BLOCK * LETTER_SZ)  // 8192 (32 KB LDS)

__global__ __launch_bounds__(BLOCK) void conv_letters_kernel(
    const float* __restrict__ x,
    const float* __restrict__ kern,
    float* __restrict__ out)
{
    __shared__ float s[IN_FLOATS_PER_BLOCK];

    const int t = threadIdx.x;
    const long long blk = blockIdx.x;

    // --- Stage 64 letters into LDS, fully coalesced float4 loads ---
    const float4* in4 = reinterpret_cast<const float4*>(x) + blk * (IN_FLOATS_PER_BLOCK / 4);
    float4* s4 = reinterpret_cast<float4*>(s);
    #pragma unroll
    for (int i = 0; i < IN_FLOATS_PER_BLOCK / 4 / BLOCK; ++i) {  // 8 iters
        s4[t + i * BLOCK] = in4[t + i * BLOCK];
    }

    // 3x3 kernel into registers (uniform, L2-cached)
    const float k0 = kern[0], k1 = kern[1], k2 = kern[2];
    const float k3 = kern[3], k4 = kern[4], k5 = kern[5];
    const float k6 = kern[6], k7 = kern[7], k8 = kern[8];

    __syncthreads();

    // --- Compute: 21 outputs per thread, lane-consecutive -> coalesced stores ---
    float* outb = out + blk * (long long)OUT_PER_BLOCK;
    #pragma unroll
    for (int i = 0; i < OUT_PER_BLOCK / BLOCK; ++i) {  // 21 iters
        const int oidx   = t + i * BLOCK;
        const int letter = oidx / OUT_PER_LETTER;
        const int within = oidx - letter * OUT_PER_LETTER;
        const int ho     = within / 6;
        const int wo     = within - ho * 6;
        const float* p = s + letter * LETTER_SZ + ho * 8 + wo;
        const float acc =
              k0 * p[0]  + k1 * p[1]  + k2 * p[2]
            + k3 * p[8]  + k4 * p[9]  + k5 * p[10]
            + k6 * p[16] + k7 * p[17] + k8 * p[18];
        outb[oidx] = acc;
    }
}

extern "C" void kernel_launch(void* const* d_in, const int* in_sizes, int n_in,
                              void* d_out, int out_size, void* d_ws, size_t ws_size,
                              hipStream_t stream) {
    const float* x    = (const float*)d_in[0];   // (512,512,128) fp32
    const float* kern = (const float*)d_in[1];   // (3,3) fp32
    float* out = (float*)d_out;                  // (1,512,512,84) fp32

    const int total_letters = in_sizes[0] / LETTER_SZ;          // 262144
    const int grid = total_letters / LETTERS_PER_BLOCK;          // 4096

    conv_letters_kernel<<<grid, BLOCK, 0, stream>>>(x, kern, out);
}

// Round 2
// 40.298 us; speedup vs baseline: 1.0058x; 1.0058x over previous
//
#include <hip/hip_runtime.h>

// 512*512 letters of 16x8 fp32; 3x3 VALID conv -> 14x6 = 84 outputs per letter.
typedef float f4 __attribute__((ext_vector_type(4)));
typedef float f2 __attribute__((ext_vector_type(2)));

#define BLOCK 256
#define LPB 64                           // letters per block
#define LETTER_SZ 128                    // floats per letter
#define IN_FLOATS (LPB * LETTER_SZ)      // 8192 floats = 32 KB
#define OUT_PER_LETTER 84
#define OUT_FLOATS (LPB * OUT_PER_LETTER) // 5376 floats = 21 KB

__global__ __launch_bounds__(BLOCK) void conv_letters_kernel(
    const float* __restrict__ x,
    const float* __restrict__ kern,
    float* __restrict__ out)
{
    // [0, IN_FLOATS): swizzled input letters; [IN_FLOATS, +OUT_FLOATS): output staging
    __shared__ float s[IN_FLOATS + OUT_FLOATS];   // 53 KB -> 3 blocks/CU

    const int t = threadIdx.x;
    const long long blk = blockIdx.x;

    // ---- Phase 1: stage 64 letters, coalesced f4 loads, XOR-swizzled LDS layout.
    // swizzle (float-index domain): fidx ^= ((letter & 7) << 2)  (letter = fidx>>7)
    // Write side: lanes 0..31 share a letter -> distinct 16B slots -> conflict-free.
    const f4* in4 = reinterpret_cast<const f4*>(x) + blk * (IN_FLOATS / 4);
    #pragma unroll
    for (int i = 0; i < IN_FLOATS / 4 / BLOCK; ++i) {   // 8 iters
        const int j = t + i * BLOCK;
        const int fidx = 4 * j;
        const int sidx = fidx ^ (((fidx >> 7) & 7) << 2);
        *reinterpret_cast<f4*>(s + sidx) = __builtin_nontemporal_load(in4 + j);
    }

    const float k0 = kern[0], k1 = kern[1], k2 = kern[2];
    const float k3 = kern[3], k4 = kern[4], k5 = kern[5];
    const float k6 = kern[6], k7 = kern[7], k8 = kern[8];

    __syncthreads();

    // ---- Phase 2: threads 0..127 each compute one half-letter (7 output rows)
    // from 9 input rows, read as swizzled ds_read_b128 pairs.
    if (t < 2 * LPB) {
        const int l = t >> 1;            // letter within block
        const int h = t & 1;             // half: rows 0..8 / 7..15
        const int sw = (l & 7) << 2;     // swizzle bits
        const int base = l * LETTER_SZ + h * 56;   // h*7 rows * 8 floats
        float* so = s + IN_FLOATS + t * 42;        // 42 contiguous outputs

        float w[3][8];                   // 3-row sliding window (static idx after unroll)

#define LOADROW(slot, ridx) do {                                            \
            const int f0_ = base + (ridx) * 8;                              \
            const f4 a_ = *reinterpret_cast<const f4*>(s + ( f0_      ^ sw)); \
            const f4 b_ = *reinterpret_cast<const f4*>(s + ((f0_ + 4) ^ sw)); \
            w[slot][0]=a_.x; w[slot][1]=a_.y; w[slot][2]=a_.z; w[slot][3]=a_.w; \
            w[slot][4]=b_.x; w[slot][5]=b_.y; w[slot][6]=b_.z; w[slot][7]=b_.w; \
        } while (0)

        LOADROW(0, 0);
        LOADROW(1, 1);

        #pragma unroll
        for (int orow = 0; orow < 7; ++orow) {
            const int R0 = orow % 3;
            const int R1 = (orow + 1) % 3;
            const int R2 = (orow + 2) % 3;
            LOADROW(R2, orow + 2);

            #pragma unroll
            for (int oc = 0; oc < 6; oc += 2) {
                f2 v;
                v.x = k0 * w[R0][oc]     + k1 * w[R0][oc + 1] + k2 * w[R0][oc + 2]
                    + k3 * w[R1][oc]     + k4 * w[R1][oc + 1] + k5 * w[R1][oc + 2]
                    + k6 * w[R2][oc]     + k7 * w[R2][oc + 1] + k8 * w[R2][oc + 2];
                v.y = k0 * w[R0][oc + 1] + k1 * w[R0][oc + 2] + k2 * w[R0][oc + 3]
                    + k3 * w[R1][oc + 1] + k4 * w[R1][oc + 2] + k5 * w[R1][oc + 3]
                    + k6 * w[R2][oc + 1] + k7 * w[R2][oc + 2] + k8 * w[R2][oc + 3];
                *reinterpret_cast<f2*>(so + orow * 6 + oc) = v;  // 8B aligned
            }
        }
#undef LOADROW
    }

    __syncthreads();

    // ---- Phase 3: fully coalesced f4 NT stores of the staged outputs.
    f4* ob = reinterpret_cast<f4*>(out + blk * (long long)OUT_FLOATS);
    const f4* so4 = reinterpret_cast<const f4*>(s + IN_FLOATS);
    #pragma unroll
    for (int i = 0; i < 6; ++i) {        // 1344 f4 / 256 threads = 5.25
        const int idx = t + i * BLOCK;
        if (idx < OUT_FLOATS / 4)
            __builtin_nontemporal_store(so4[idx], ob + idx);
    }
}

extern "C" void kernel_launch(void* const* d_in, const int* in_sizes, int n_in,
                              void* d_out, int out_size, void* d_ws, size_t ws_size,
                              hipStream_t stream) {
    const float* x    = (const float*)d_in[0];   // (512,512,128) fp32
    const float* kern = (const float*)d_in[1];   // (3,3) fp32
    float* out = (float*)d_out;                  // (1,512,512,84) fp32

    const int total_letters = in_sizes[0] / LETTER_SZ;   // 262144
    const int grid = total_letters / LPB;                 // 4096

    conv_letters_kernel<<<grid, BLOCK, 0, stream>>>(x, kern, out);
}